// Round 1
// baseline (69640.509 us; speedup 1.0000x reference)
//
#include <hip/hip_runtime.h>

typedef _Float16 f16;
typedef _Float16 f16x8 __attribute__((ext_vector_type(8)));
typedef float f32x4 __attribute__((ext_vector_type(4)));

#define T_STEPS 1024
#define BATCH 128
#define DIN 512
#define HID 1024
#define OUTD 128

#define APITCH 264   // f16 per Alds row (256 + 8 pad -> 132-dword stride, 2-way bank alias = free)
#define ZPITCH 33

// ---- workspace layout (bytes) ----
#define OFF_WP1 0L          // packed [Wih1|Whh1], 4096 cols x 1536 K, f16 : 12582912
#define OFF_WP2 12582912L   // packed [Wih2|Whh2], 4096 cols x 2048 K, f16 : 16777216
#define OFF_WPO 29360128L   // packed Wout, 128 cols x 1024 K, f16       : 262144
#define OFF_B1  29622272L   // bias1 (permuted b_ih1+b_hh1) f32          : 16384
#define OFF_B2  29638656L   // bias2 f32                                  : 16384
#define OFF_H1H 29655040L   // h1 fp16, 2 slots x 128 x 1024              : 524288
#define OFF_H2H 30179328L   // h2 fp16, 2 slots x 128 x 1024              : 524288
#define OFF_BAR 30703616L   // barrier: 8 counters (stride 32 ints) + gen at [256]

// packed column permutation: packed col p -> orig col = gate*1024 + unit
// p: q=p>>5 (unit-group of 8), r=p&31, gate=r>>3, unit=q*8+(r&7)
__device__ __host__ inline int col_perm(int p) {
    int q = p >> 5, r = p & 31;
    return (r >> 3) * 1024 + q * 8 + (r & 7);
}

// ------------------- prep kernel: pack weights/biases, zero h and barrier -------------------
__global__ void pack_kernel(const float* __restrict__ Wih1, const float* __restrict__ Whh1,
                            const float* __restrict__ Wih2, const float* __restrict__ Whh2,
                            const float* __restrict__ Wout,
                            const float* __restrict__ bih1, const float* __restrict__ bhh1,
                            const float* __restrict__ bih2, const float* __restrict__ bhh2,
                            f16* Wp1, f16* Wp2, f16* Wpo, float* bias1, float* bias2,
                            f16* h1h, f16* h2h, int* bar)
{
    long idx = (long)blockIdx.x * 256 + threadIdx.x;
    const long NW1 = 786432, NW2 = 1048576, NWO = 16384;
    if (idx < NW1) {  // Wp1: blocks = 256 nb * 48 kb
        long blk = idx >> 6; int lane = idx & 63;
        int nb = (int)(blk / 48), kb = (int)(blk % 48);
        int p = nb * 16 + (lane & 15);
        int k = kb * 32 + (lane >> 4) * 8;
        int n = col_perm(p);
        f16x8 v;
        #pragma unroll
        for (int j = 0; j < 8; j++) {
            int kk = k + j;
            float wv = (kk < 512) ? Wih1[(size_t)n * 512 + kk] : Whh1[(size_t)n * 1024 + kk - 512];
            v[j] = (f16)wv;
        }
        *(f16x8*)(Wp1 + blk * 512 + lane * 8) = v;
        return;
    }
    idx -= NW1;
    if (idx < NW2) {  // Wp2: 256 nb * 64 kb
        long blk = idx >> 6; int lane = idx & 63;
        int nb = (int)(blk / 64), kb = (int)(blk % 64);
        int p = nb * 16 + (lane & 15);
        int k = kb * 32 + (lane >> 4) * 8;
        int n = col_perm(p);
        f16x8 v;
        #pragma unroll
        for (int j = 0; j < 8; j++) {
            int kk = k + j;
            float wv = (kk < 1024) ? Wih2[(size_t)n * 1024 + kk] : Whh2[(size_t)n * 1024 + kk - 1024];
            v[j] = (f16)wv;
        }
        *(f16x8*)(Wp2 + blk * 512 + lane * 8) = v;
        return;
    }
    idx -= NW2;
    if (idx < NWO) {  // Wpo: 8 nb * 32 kb, no permutation
        long blk = idx >> 6; int lane = idx & 63;
        int nb = (int)(blk / 32), kb = (int)(blk % 32);
        int n = nb * 16 + (lane & 15);
        int k = kb * 32 + (lane >> 4) * 8;
        f16x8 v;
        #pragma unroll
        for (int j = 0; j < 8; j++) v[j] = (f16)Wout[(size_t)n * 1024 + k + j];
        *(f16x8*)(Wpo + blk * 512 + lane * 8) = v;
        return;
    }
    idx -= NWO;
    if (idx < 4096) { int n = col_perm((int)idx); bias1[idx] = bih1[n] + bhh1[n]; return; }
    idx -= 4096;
    if (idx < 4096) { int n = col_perm((int)idx); bias2[idx] = bih2[n] + bhh2[n]; return; }
    idx -= 4096;
    if (idx < 65536) {  // zero both slots of h1h and h2h (h_{-1} = 0)
        f16x8 z = {};
        if (idx < 32768) *(f16x8*)(h1h + idx * 8) = z;
        else             *(f16x8*)(h2h + (idx - 32768) * 8) = z;
        return;
    }
    idx -= 65536;
    if (idx < 512) bar[idx] = 0;
}

// ------------------- grid barrier: 8 split cumulative counters + generation -------------------
__device__ __forceinline__ void gridbar(int* bar, int p)
{
    __syncthreads();
    if (threadIdx.x == 0) {
        int* gen = bar + 256;
        const int slot = (blockIdx.x & 7) * 32;
        __hip_atomic_fetch_add(bar + slot, 1, __ATOMIC_RELEASE, __HIP_MEMORY_SCOPE_AGENT);
        if (blockIdx.x == 0) {
            const int tgt = 32 * (p + 1);
            for (int k = 0; k < 8; k++)
                while (__hip_atomic_load(bar + k * 32, __ATOMIC_RELAXED, __HIP_MEMORY_SCOPE_AGENT) < tgt)
                    __builtin_amdgcn_s_sleep(1);
            __hip_atomic_store(gen, p + 1, __ATOMIC_RELEASE, __HIP_MEMORY_SCOPE_AGENT);
        } else {
            while (__hip_atomic_load(gen, __ATOMIC_RELAXED, __HIP_MEMORY_SCOPE_AGENT) < p + 1)
                __builtin_amdgcn_s_sleep(1);
        }
        __builtin_amdgcn_fence(__ATOMIC_ACQUIRE, "agent");
    }
    __syncthreads();
}

// ------------------- A-operand staging: 128 rows x 256 k chunk into LDS (fp16) -------------------
__device__ __forceinline__ void stage_chunk(f16* Alds, int ch, int nx, int nA,
                                            const float* xsrc, const f16* hA, const f16* hB)
{
    #pragma unroll 8
    for (int it = 0; it < 16; it++) {
        int g = threadIdx.x + it * 256;   // 0..4095 : b = g>>5, k-octet = g&31
        int b = g >> 5, k8 = g & 31;
        f16x8 v;
        if (ch < nx) {
            const float* s = xsrc + (size_t)b * DIN + ch * 256 + k8 * 8;
            float4 u0 = *(const float4*)s;
            float4 u1 = *(const float4*)(s + 4);
            v[0] = (f16)u0.x; v[1] = (f16)u0.y; v[2] = (f16)u0.z; v[3] = (f16)u0.w;
            v[4] = (f16)u1.x; v[5] = (f16)u1.y; v[6] = (f16)u1.z; v[7] = (f16)u1.w;
        } else if (ch < nx + nA) {
            v = *(const f16x8*)(hA + (size_t)b * HID + (ch - nx) * 256 + k8 * 8);
        } else {
            v = *(const f16x8*)(hB + (size_t)b * HID + (ch - nx - nA) * 256 + k8 * 8);
        }
        *(f16x8*)&Alds[b * APITCH + k8 * 8] = v;
    }
}

// ------------------- GEMM over K chunks; B from packed global, A via LDS -------------------
template<bool TWON>
__device__ __forceinline__ void run_gemm(f16* Alds, const f16* Wp, int nb0, int nchunks, int Kt32,
                                         int nx, int nA, const float* xsrc, const f16* hA, const f16* hB,
                                         f32x4 acc[2][2])
{
    const int lane = threadIdx.x & 63, wave = threadIdx.x >> 6;
    const int abase = (wave * 32 + (lane & 15)) * APITCH + (lane >> 4) * 8;
    const f16* B0 = Wp + (size_t)nb0 * Kt32 * 512 + lane * 8;
    const f16* B1 = B0 + (size_t)Kt32 * 512;
    for (int ch = 0; ch < nchunks; ch++) {
        __syncthreads();
        stage_chunk(Alds, ch, nx, nA, xsrc, hA, hB);
        __syncthreads();
        #pragma unroll
        for (int kb = 0; kb < 8; kb++) {
            int kq = ch * 8 + kb;
            f16x8 a0 = *(const f16x8*)&Alds[abase + kb * 32];
            f16x8 a1 = *(const f16x8*)&Alds[abase + 16 * APITCH + kb * 32];
            f16x8 b0 = *(const f16x8*)(B0 + (size_t)kq * 512);
            acc[0][0] = __builtin_amdgcn_mfma_f32_16x16x32_f16(a0, b0, acc[0][0], 0, 0, 0);
            acc[1][0] = __builtin_amdgcn_mfma_f32_16x16x32_f16(a1, b0, acc[1][0], 0, 0, 0);
            if (TWON) {
                f16x8 b1 = *(const f16x8*)(B1 + (size_t)kq * 512);
                acc[0][1] = __builtin_amdgcn_mfma_f32_16x16x32_f16(a0, b1, acc[0][1], 0, 0, 0);
                acc[1][1] = __builtin_amdgcn_mfma_f32_16x16x32_f16(a1, b1, acc[1][1], 0, 0, 0);
            }
        }
    }
}

template<bool TWON>
__device__ __forceinline__ void acc_to_zl(float* zl, f32x4 acc[2][2])
{
    const int lane = threadIdx.x & 63, wave = threadIdx.x >> 6;
    #pragma unroll
    for (int mt = 0; mt < 2; mt++)
        #pragma unroll
        for (int nt = 0; nt < (TWON ? 2 : 1); nt++)
            #pragma unroll
            for (int r = 0; r < 4; r++) {
                int row = wave * 32 + mt * 16 + (lane >> 4) * 4 + r;
                int col = nt * 16 + (lane & 15);
                zl[row * ZPITCH + col] = acc[mt][nt][r];
            }
}

__device__ __forceinline__ float sigm(float v) { return 1.f / (1.f + __expf(-v)); }
__device__ __forceinline__ float tanh_f(float v) { return 1.f - 2.f / (__expf(2.f * v) + 1.f); }

// elementwise LSTM gate update for this WG's 8 units x 128 batch
__device__ __forceinline__ void do_ew(const float* zl, float* cst, const float* biasp, int p0,
                                      f16* hdst, int u0)
{
    const int j = threadIdx.x & 7;
    const int bb = threadIdx.x >> 3;
    #pragma unroll
    for (int i = 0; i < 4; i++) {
        const int b = bb * 4 + i;
        float zi = zl[b * ZPITCH + j]      + biasp[p0 + j];
        float zf = zl[b * ZPITCH + 8 + j]  + biasp[p0 + 8 + j];
        float zg = zl[b * ZPITCH + 16 + j] + biasp[p0 + 16 + j];
        float zo = zl[b * ZPITCH + 24 + j] + biasp[p0 + 24 + j];
        float c  = cst[b * 8 + j];
        float cn = sigm(zf) * c + sigm(zi) * tanh_f(zg);
        float h  = sigm(zo) * tanh_f(cn);
        cst[b * 8 + j] = cn;
        hdst[(size_t)b * HID + u0 + j] = (f16)h;
    }
}

// ------------------- persistent pipelined LSTM kernel -------------------
__global__ void __launch_bounds__(256, 1) lstm_persist(
    const float* __restrict__ x, const float* __restrict__ b_out,
    const f16* __restrict__ Wp1, const f16* __restrict__ Wp2, const f16* __restrict__ Wpo,
    const float* __restrict__ bias1, const float* __restrict__ bias2,
    f16* h1h, f16* h2h, int* bar, float* __restrict__ out)
{
    __shared__ f16 Alds[128 * APITCH];     // 67584 B
    __shared__ float zl[128 * ZPITCH];     // 16896 B
    __shared__ float cst[128 * 8];         // 4096 B  (persistent c-state for this WG's 8 units)

    const int w = blockIdx.x;
    const bool isL1 = (w < 128);
    const int wl = isL1 ? w : (w - 128);
    const int u0 = wl * 8;

    for (int i = threadIdx.x; i < 1024; i += 256) cst[i] = 0.f;
    __syncthreads();

    for (int p = 0; p < T_STEPS + 2; p++) {
        if (isL1) {
            if (p < T_STEPS) {
                const int t1 = p;
                const f16* h1prev = h1h + (size_t)((t1 - 1) & 1) * BATCH * HID;
                const float* xsrc = x + (size_t)t1 * BATCH * DIN;
                f32x4 acc[2][2] = {};
                run_gemm<true>(Alds, Wp1, 2 * w, 6, 48, 2, 4, xsrc, h1prev, h1prev, acc);
                acc_to_zl<true>(zl, acc);
                __syncthreads();
                do_ew(zl, cst, bias1, w * 32, h1h + (size_t)(t1 & 1) * BATCH * HID, u0);
            }
            if (w < 8 && p >= 2) {
                const int ty = p - 2;
                const f16* h2y = h2h + (size_t)(ty & 1) * BATCH * HID;
                f32x4 acc2[2][2] = {};
                run_gemm<false>(Alds, Wpo, w, 4, 32, 0, 4, nullptr, h2y, h2y, acc2);
                acc_to_zl<false>(zl, acc2);
                __syncthreads();
                int b = threadIdx.x >> 1, oh = (threadIdx.x & 1) * 8;
                float* dst = out + ((size_t)ty * BATCH + b) * OUTD + w * 16 + oh;
                const float* bo = b_out + w * 16 + oh;
                float4 r0, r1;
                r0.x = zl[b * ZPITCH + oh + 0] + bo[0];
                r0.y = zl[b * ZPITCH + oh + 1] + bo[1];
                r0.z = zl[b * ZPITCH + oh + 2] + bo[2];
                r0.w = zl[b * ZPITCH + oh + 3] + bo[3];
                r1.x = zl[b * ZPITCH + oh + 4] + bo[4];
                r1.y = zl[b * ZPITCH + oh + 5] + bo[5];
                r1.z = zl[b * ZPITCH + oh + 6] + bo[6];
                r1.w = zl[b * ZPITCH + oh + 7] + bo[7];
                *(float4*)dst = r0;
                *(float4*)(dst + 4) = r1;
            }
        } else {
            const int t2 = p - 1;
            if (t2 >= 0 && t2 < T_STEPS) {
                const f16* h1cur  = h1h + (size_t)(t2 & 1) * BATCH * HID;
                const f16* h2prev = h2h + (size_t)((t2 - 1) & 1) * BATCH * HID;
                f32x4 acc[2][2] = {};
                run_gemm<true>(Alds, Wp2, 2 * wl, 8, 64, 0, 4, nullptr, h1cur, h2prev, acc);
                acc_to_zl<true>(zl, acc);
                __syncthreads();
                do_ew(zl, cst, bias2, wl * 32, h2h + (size_t)(t2 & 1) * BATCH * HID, u0);
            }
        }
        gridbar(bar, p);
    }
}

extern "C" void kernel_launch(void* const* d_in, const int* in_sizes, int n_in,
                              void* d_out, int out_size, void* d_ws, size_t ws_size,
                              hipStream_t stream)
{
    const float* x    = (const float*)d_in[0];
    const float* Wih1 = (const float*)d_in[1];
    const float* Whh1 = (const float*)d_in[2];
    const float* bih1 = (const float*)d_in[3];
    const float* bhh1 = (const float*)d_in[4];
    const float* Wih2 = (const float*)d_in[5];
    const float* Whh2 = (const float*)d_in[6];
    const float* bih2 = (const float*)d_in[7];
    const float* bhh2 = (const float*)d_in[8];
    const float* Wout = (const float*)d_in[9];
    const float* bout = (const float*)d_in[10];

    char* ws = (char*)d_ws;
    f16*   Wp1 = (f16*)(ws + OFF_WP1);
    f16*   Wp2 = (f16*)(ws + OFF_WP2);
    f16*   Wpo = (f16*)(ws + OFF_WPO);
    float* b1  = (float*)(ws + OFF_B1);
    float* b2  = (float*)(ws + OFF_B2);
    f16*   h1h = (f16*)(ws + OFF_H1H);
    f16*   h2h = (f16*)(ws + OFF_H2H);
    int*   bar = (int*)(ws + OFF_BAR);
    float* out = (float*)d_out;

    hipLaunchKernelGGL(pack_kernel, dim3(7522), dim3(256), 0, stream,
                       Wih1, Whh1, Wih2, Whh2, Wout, bih1, bhh1, bih2, bhh2,
                       Wp1, Wp2, Wpo, b1, b2, h1h, h2h, bar);

    void* args[] = { (void*)&x, (void*)&bout, (void*)&Wp1, (void*)&Wp2, (void*)&Wpo,
                     (void*)&b1, (void*)&b2, (void*)&h1h, (void*)&h2h, (void*)&bar, (void*)&out };
    hipError_t e = hipLaunchCooperativeKernel((void*)lstm_persist, dim3(256), dim3(256), args, 0, stream);
    if (e != hipSuccess) {
        // fallback: plain launch — 256 one-per-CU blocks are co-resident on a 256-CU device
        hipLaunchKernelGGL(lstm_persist, dim3(256), dim3(256), 0, stream,
                           x, bout, Wp1, Wp2, Wpo, b1, b2, h1h, h2h, bar, out);
    }
}

// Round 2
// 29817.441 us; speedup vs baseline: 2.3356x; 2.3356x over previous
//
#include <hip/hip_runtime.h>

typedef _Float16 f16;
typedef _Float16 f16x8 __attribute__((ext_vector_type(8)));
typedef float f32x4 __attribute__((ext_vector_type(4)));

#define T_STEPS 1024
#define BATCH 128
#define DIN 512
#define HID 1024
#define OUTD 128

// ---- workspace layout (bytes) ----
#define OFF_WP1 0L          // packed [Wih1|Whh1]: 256 nb x 48 kq x 512 f16 = 12582912 B
#define OFF_WP2 12582912L   // packed [Wih2|Whh2]: 256 nb x 64 kq x 512 f16 = 16777216 B
#define OFF_WPO 29360128L   // packed Wout: 8 nb x 32 kq x 512 f16 = 262144 B
#define OFF_B1  29622272L   // bias1 (permuted) f32 : 16384 B
#define OFF_B2  29638656L   // bias2 f32 : 16384 B
#define OFF_H1H 29655040L   // h1 f16, 2 slots x 128 x 1024 : 524288 B
#define OFF_H2H 30179328L   // h2 f16, 2 slots x 128 x 1024 : 524288 B
#define OFF_BAR 30703616L   // barrier: 64 slots x 32 ints + gen @ [2048]; 4096 ints
#define OFF_ZP  30720000L   // y partials: [par2][half2][cb8][128][16] f32 = 262144 B

// packed col permutation: packed col p -> orig col = gate*1024 + unit
__device__ __host__ inline int col_perm(int p) {
    int q = p >> 5, r = p & 31;
    return (r >> 3) * 1024 + q * 8 + (r & 7);
}

// ------------------- prep kernel -------------------
__global__ void pack_kernel(const float* __restrict__ Wih1, const float* __restrict__ Whh1,
                            const float* __restrict__ Wih2, const float* __restrict__ Whh2,
                            const float* __restrict__ Wout,
                            const float* __restrict__ bih1, const float* __restrict__ bhh1,
                            const float* __restrict__ bih2, const float* __restrict__ bhh2,
                            f16* Wp1, f16* Wp2, f16* Wpo, float* bias1, float* bias2,
                            f16* h1h, f16* h2h, int* bar)
{
    long idx = (long)blockIdx.x * 256 + threadIdx.x;
    const long NW1 = 786432, NW2 = 1048576, NWO = 16384;
    if (idx < NW1) {  // Wp1: 256 nb * 48 kb blocks of 64 lanes
        long blk = idx >> 6; int lane = idx & 63;
        int nb = (int)(blk / 48), kb = (int)(blk % 48);
        int p = nb * 16 + (lane & 15);
        int k = kb * 32 + (lane >> 4) * 8;
        int n = col_perm(p);
        f16x8 v;
        #pragma unroll
        for (int j = 0; j < 8; j++) {
            int kk = k + j;
            float wv = (kk < 512) ? Wih1[(size_t)n * 512 + kk] : Whh1[(size_t)n * 1024 + kk - 512];
            v[j] = (f16)wv;
        }
        *(f16x8*)(Wp1 + blk * 512 + lane * 8) = v;
        return;
    }
    idx -= NW1;
    if (idx < NW2) {  // Wp2: 256 nb * 64 kb
        long blk = idx >> 6; int lane = idx & 63;
        int nb = (int)(blk / 64), kb = (int)(blk % 64);
        int p = nb * 16 + (lane & 15);
        int k = kb * 32 + (lane >> 4) * 8;
        int n = col_perm(p);
        f16x8 v;
        #pragma unroll
        for (int j = 0; j < 8; j++) {
            int kk = k + j;
            float wv = (kk < 1024) ? Wih2[(size_t)n * 1024 + kk] : Whh2[(size_t)n * 1024 + kk - 1024];
            v[j] = (f16)wv;
        }
        *(f16x8*)(Wp2 + blk * 512 + lane * 8) = v;
        return;
    }
    idx -= NW2;
    if (idx < NWO) {  // Wpo: 8 nb * 32 kb, identity cols
        long blk = idx >> 6; int lane = idx & 63;
        int nb = (int)(blk / 32), kb = (int)(blk % 32);
        int n = nb * 16 + (lane & 15);
        int k = kb * 32 + (lane >> 4) * 8;
        f16x8 v;
        #pragma unroll
        for (int j = 0; j < 8; j++) v[j] = (f16)Wout[(size_t)n * 1024 + k + j];
        *(f16x8*)(Wpo + blk * 512 + lane * 8) = v;
        return;
    }
    idx -= NWO;
    if (idx < 4096) { int n = col_perm((int)idx); bias1[idx] = bih1[n] + bhh1[n]; return; }
    idx -= 4096;
    if (idx < 4096) { int n = col_perm((int)idx); bias2[idx] = bih2[n] + bhh2[n]; return; }
    idx -= 4096;
    if (idx < 65536) {  // zero both parity slots of h1h/h2h
        f16x8 z = {};
        if (idx < 32768) *(f16x8*)(h1h + idx * 8) = z;
        else             *(f16x8*)(h2h + (idx - 32768) * 8) = z;
        return;
    }
    idx -= 65536;
    if (idx < 4096) bar[idx] = 0;
}

// ------------------- grid barrier: 64 slots, wave-parallel poll in WG0 -------------------
__device__ __forceinline__ void gridbar(int* bar, int p)
{
    __syncthreads();
    const int tid = threadIdx.x;
    int* gen = bar + 2048;
    if (blockIdx.x == 0) {
        if (tid == 0)
            __hip_atomic_fetch_add(bar + 0, 1, __ATOMIC_RELEASE, __HIP_MEMORY_SCOPE_AGENT);
        if (tid < 64) {
            const int tgt = 4 * (p + 1);   // 256 WGs / 64 slots = 4 per slot
            while (__hip_atomic_load(bar + tid * 32, __ATOMIC_RELAXED, __HIP_MEMORY_SCOPE_AGENT) < tgt)
                __builtin_amdgcn_s_sleep(1);
            if (tid == 0) {
                __builtin_amdgcn_fence(__ATOMIC_ACQUIRE, "agent");
                __hip_atomic_store(gen, p + 1, __ATOMIC_RELEASE, __HIP_MEMORY_SCOPE_AGENT);
            }
        }
    } else {
        if (tid == 0) {
            __hip_atomic_fetch_add(bar + (blockIdx.x & 63) * 32, 1, __ATOMIC_RELEASE, __HIP_MEMORY_SCOPE_AGENT);
            while (__hip_atomic_load(gen, __ATOMIC_RELAXED, __HIP_MEMORY_SCOPE_AGENT) < p + 1)
                __builtin_amdgcn_s_sleep(1);
            __builtin_amdgcn_fence(__ATOMIC_ACQUIRE, "agent");
        }
    }
    __syncthreads();
}

// ------------------- LDS weight copy -------------------
__device__ __forceinline__ void ldcopy(f16* dst, const f16* src, int nelem)
{
    for (int i = threadIdx.x * 8; i < nelem; i += 256 * 8)
        *(f16x8*)(dst + i) = *(const f16x8*)(src + i);
}

// ------------------- A-fragment chunk loaders (8 kq = 256 K-elems, 2 m-tiles) -------------------
__device__ __forceinline__ void loadA_f16(f16x8 buf[2][8], const f16* src, int strideE, int kOff)
{
    const int lane = threadIdx.x & 63, wave = threadIdx.x >> 6;
    const int r0 = wave * 32 + (lane & 15);
    const f16* p0 = src + (size_t)r0 * strideE + kOff + (lane >> 4) * 8;
    const f16* p1 = p0 + (size_t)16 * strideE;
    #pragma unroll
    for (int kb = 0; kb < 8; kb++) {
        buf[0][kb] = *(const f16x8*)(p0 + kb * 32);
        buf[1][kb] = *(const f16x8*)(p1 + kb * 32);
    }
}

__device__ __forceinline__ void loadA_f32(f16x8 buf[2][8], const float* src, int strideE, int kOff)
{
    const int lane = threadIdx.x & 63, wave = threadIdx.x >> 6;
    const int r0 = wave * 32 + (lane & 15);
    const float* p0 = src + (size_t)r0 * strideE + kOff + (lane >> 4) * 8;
    const float* p1 = p0 + (size_t)16 * strideE;
    #pragma unroll
    for (int kb = 0; kb < 8; kb++) {
        float4 u0 = *(const float4*)(p0 + kb * 32);
        float4 u1 = *(const float4*)(p0 + kb * 32 + 4);
        float4 w0 = *(const float4*)(p1 + kb * 32);
        float4 w1 = *(const float4*)(p1 + kb * 32 + 4);
        f16x8 a, b;
        a[0]=(f16)u0.x; a[1]=(f16)u0.y; a[2]=(f16)u0.z; a[3]=(f16)u0.w;
        a[4]=(f16)u1.x; a[5]=(f16)u1.y; a[6]=(f16)u1.z; a[7]=(f16)u1.w;
        b[0]=(f16)w0.x; b[1]=(f16)w0.y; b[2]=(f16)w0.z; b[3]=(f16)w0.w;
        b[4]=(f16)w1.x; b[5]=(f16)w1.y; b[6]=(f16)w1.z; b[7]=(f16)w1.w;
        buf[0][kb] = a;
        buf[1][kb] = b;
    }
}

// ------------------- compute one 8-kq chunk from register A-buffer + LDS B -------------------
template<bool TWON>
__device__ __forceinline__ void computeChunk(const f16* B0, const f16* B1, int kqBase,
                                             f16x8 buf[2][8], f32x4 acc[2][2])
{
    const int lane = threadIdx.x & 63;
    #pragma unroll
    for (int kb = 0; kb < 8; kb++) {
        const int kq = kqBase + kb;
        f16x8 b0 = *(const f16x8*)(B0 + (size_t)kq * 512 + lane * 8);
        acc[0][0] = __builtin_amdgcn_mfma_f32_16x16x32_f16(buf[0][kb], b0, acc[0][0], 0, 0, 0);
        acc[1][0] = __builtin_amdgcn_mfma_f32_16x16x32_f16(buf[1][kb], b0, acc[1][0], 0, 0, 0);
        if (TWON) {
            f16x8 b1 = *(const f16x8*)(B1 + (size_t)kq * 512 + lane * 8);
            acc[0][1] = __builtin_amdgcn_mfma_f32_16x16x32_f16(buf[0][kb], b1, acc[0][1], 0, 0, 0);
            acc[1][1] = __builtin_amdgcn_mfma_f32_16x16x32_f16(buf[1][kb], b1, acc[1][1], 0, 0, 0);
        }
    }
}

// ------------------- GEMM over one A-region, register double-buffered (nch even) -------------------
template<bool TWON, bool F32>
__device__ __forceinline__ void gemm_region(const void* src, int strideE, int kOff0, int kqBase, int nch,
                                            const f16* B0, const f16* B1, f32x4 acc[2][2])
{
    f16x8 bufA[2][8], bufB[2][8];
    if (F32) loadA_f32(bufA, (const float*)src, strideE, kOff0);
    else     loadA_f16(bufA, (const f16*)src, strideE, kOff0);
    for (int c = 0; c < nch; c += 2) {
        if (F32) loadA_f32(bufB, (const float*)src, strideE, kOff0 + (c + 1) * 256);
        else     loadA_f16(bufB, (const f16*)src, strideE, kOff0 + (c + 1) * 256);
        computeChunk<TWON>(B0, B1, kqBase + c * 8, bufA, acc);
        if (c + 2 < nch) {
            if (F32) loadA_f32(bufA, (const float*)src, strideE, kOff0 + (c + 2) * 256);
            else     loadA_f16(bufA, (const f16*)src, strideE, kOff0 + (c + 2) * 256);
        }
        computeChunk<TWON>(B0, B1, kqBase + (c + 1) * 8, bufB, acc);
    }
}

template<bool TWON>
__device__ __forceinline__ void acc_to_zl(float* zl, f32x4 acc[2][2])
{
    const int lane = threadIdx.x & 63, wave = threadIdx.x >> 6;
    #pragma unroll
    for (int mt = 0; mt < 2; mt++)
        #pragma unroll
        for (int nt = 0; nt < (TWON ? 2 : 1); nt++)
            #pragma unroll
            for (int r = 0; r < 4; r++) {
                int row = wave * 32 + mt * 16 + (lane >> 4) * 4 + r;
                int col = nt * 16 + (lane & 15);
                zl[row * 33 + col] = acc[mt][nt][r];
            }
}

__device__ __forceinline__ float sigm(float v) { return 1.f / (1.f + __expf(-v)); }
__device__ __forceinline__ float tanh_f(float v) { return 1.f - 2.f / (__expf(2.f * v) + 1.f); }

__device__ __forceinline__ void do_ew(const float* zl, float* cst, const float* biasp, int p0,
                                      f16* hdst, int u0)
{
    const int j = threadIdx.x & 7;
    const int bb = threadIdx.x >> 3;
    #pragma unroll
    for (int i = 0; i < 4; i++) {
        const int b = bb * 4 + i;
        float zi = zl[b * 33 + j]      + biasp[p0 + j];
        float zf = zl[b * 33 + 8 + j]  + biasp[p0 + 8 + j];
        float zg = zl[b * 33 + 16 + j] + biasp[p0 + 16 + j];
        float zo = zl[b * 33 + 24 + j] + biasp[p0 + 24 + j];
        float c  = cst[b * 8 + j];
        float cn = sigm(zf) * c + sigm(zi) * tanh_f(zg);
        float h  = sigm(zo) * tanh_f(cn);
        cst[b * 8 + j] = cn;
        hdst[(size_t)b * HID + u0 + j] = (f16)h;
    }
}

// ------------------- persistent pipelined LSTM kernel -------------------
__global__ void __launch_bounds__(256, 1) lstm_persist(
    const float* __restrict__ x, const float* __restrict__ b_out,
    const f16* __restrict__ Wp1, const f16* __restrict__ Wp2, const f16* __restrict__ Wpo,
    const float* __restrict__ bias1, const float* __restrict__ bias2,
    f16* h1h, f16* h2h, int* bar, float* zpart, float* __restrict__ out)
{
    __shared__ f16 Wlds[65536];        // 128 KB: L1 WG: 96 KB W1 + (w<16) 16 KB Wout-slice; L2 WG: 128 KB W2
    __shared__ float zl[128 * 33];     // 16896 B
    __shared__ float cst[1024];        // 4 KB persistent c-state (this WG's 8 units x 128 batch)

    const int w = blockIdx.x;
    const bool isL1 = (w < 128);
    const int wl = isL1 ? w : (w - 128);

    if (isL1) {
        ldcopy(Wlds, Wp1 + (size_t)w * 49152, 49152);
        if (w < 16)
            ldcopy(Wlds + 49152, Wpo + ((size_t)(w & 7) * 32 + (w >> 3) * 16) * 512, 8192);
    } else {
        ldcopy(Wlds, Wp2 + (size_t)wl * 65536, 65536);
    }
    for (int i = threadIdx.x; i < 1024; i += 256) cst[i] = 0.f;
    __syncthreads();

    const f16* B0 = Wlds;
    const f16* B1 = isL1 ? (Wlds + 48 * 512) : (Wlds + 64 * 512);
    const f16* Bo = Wlds + 49152;

    for (int p = 0; p < T_STEPS + 3; p++) {
        if (isL1) {
            if (p < T_STEPS) {
                const int t1 = p;
                const f16* h1prev = h1h + (size_t)((t1 + 1) & 1) * (BATCH * HID);
                f32x4 acc[2][2] = {};
                gemm_region<true, true >(x + (size_t)t1 * BATCH * DIN, DIN, 0, 0, 2, B0, B1, acc);
                gemm_region<true, false>(h1prev, HID, 0, 16, 4, B0, B1, acc);
                __syncthreads();
                acc_to_zl<true>(zl, acc);
                __syncthreads();
                do_ew(zl, cst, bias1, w * 32, h1h + (size_t)(t1 & 1) * (BATCH * HID), w * 8);
            }
            if (w < 16 && p >= 2 && p < T_STEPS + 2) {
                const int ty = p - 2;
                const f16* h2y = h2h + (size_t)(ty & 1) * (BATCH * HID);
                f32x4 acc2[2][2] = {};
                gemm_region<false, false>(h2y, HID, (w >> 3) * 512, 0, 2, Bo, Bo, acc2);
                __syncthreads();
                acc_to_zl<false>(zl, acc2);
                __syncthreads();
                float* zp = zpart + (((size_t)(ty & 1) * 2 + (w >> 3)) * 8 + (w & 7)) * 2048;
                int b = threadIdx.x >> 1, oh = (threadIdx.x & 1) * 8;
                float4 r0, r1;
                r0.x = zl[b * 33 + oh + 0]; r0.y = zl[b * 33 + oh + 1];
                r0.z = zl[b * 33 + oh + 2]; r0.w = zl[b * 33 + oh + 3];
                r1.x = zl[b * 33 + oh + 4]; r1.y = zl[b * 33 + oh + 5];
                r1.z = zl[b * 33 + oh + 6]; r1.w = zl[b * 33 + oh + 7];
                *(float4*)(zp + b * 16 + oh) = r0;
                *(float4*)(zp + b * 16 + oh + 4) = r1;
            }
            if (w < 8 && p >= 3) {
                const int to = p - 3;
                const float* zp0 = zpart + (((size_t)(to & 1) * 2 + 0) * 8 + w) * 2048;
                const float* zp1 = zpart + (((size_t)(to & 1) * 2 + 1) * 8 + w) * 2048;
                int b = threadIdx.x >> 1, oh = (threadIdx.x & 1) * 8;
                const float* bo = b_out + w * 16 + oh;
                float* dst = out + ((size_t)to * BATCH + b) * OUTD + w * 16 + oh;
                float4 r0, r1;
                r0.x = zp0[b * 16 + oh + 0] + zp1[b * 16 + oh + 0] + bo[0];
                r0.y = zp0[b * 16 + oh + 1] + zp1[b * 16 + oh + 1] + bo[1];
                r0.z = zp0[b * 16 + oh + 2] + zp1[b * 16 + oh + 2] + bo[2];
                r0.w = zp0[b * 16 + oh + 3] + zp1[b * 16 + oh + 3] + bo[3];
                r1.x = zp0[b * 16 + oh + 4] + zp1[b * 16 + oh + 4] + bo[4];
                r1.y = zp0[b * 16 + oh + 5] + zp1[b * 16 + oh + 5] + bo[5];
                r1.z = zp0[b * 16 + oh + 6] + zp1[b * 16 + oh + 6] + bo[6];
                r1.w = zp0[b * 16 + oh + 7] + zp1[b * 16 + oh + 7] + bo[7];
                *(float4*)dst = r0;
                *(float4*)(dst + 4) = r1;
            }
        } else {
            const int t2 = p - 1;
            if (t2 >= 0 && t2 < T_STEPS) {
                const f16* h1cur  = h1h + (size_t)(t2 & 1) * (BATCH * HID);
                const f16* h2prev = h2h + (size_t)((t2 + 1) & 1) * (BATCH * HID);
                f32x4 acc[2][2] = {};
                gemm_region<true, false>(h1cur,  HID, 0, 0,  4, B0, B1, acc);
                gemm_region<true, false>(h2prev, HID, 0, 32, 4, B0, B1, acc);
                __syncthreads();
                acc_to_zl<true>(zl, acc);
                __syncthreads();
                do_ew(zl, cst, bias2, wl * 32, h2h + (size_t)(t2 & 1) * (BATCH * HID), wl * 8);
            }
        }
        gridbar(bar, p);
    }
}

extern "C" void kernel_launch(void* const* d_in, const int* in_sizes, int n_in,
                              void* d_out, int out_size, void* d_ws, size_t ws_size,
                              hipStream_t stream)
{
    const float* x    = (const float*)d_in[0];
    const float* Wih1 = (const float*)d_in[1];
    const float* Whh1 = (const float*)d_in[2];
    const float* bih1 = (const float*)d_in[3];
    const float* bhh1 = (const float*)d_in[4];
    const float* Wih2 = (const float*)d_in[5];
    const float* Whh2 = (const float*)d_in[6];
    const float* bih2 = (const float*)d_in[7];
    const float* bhh2 = (const float*)d_in[8];
    const float* Wout = (const float*)d_in[9];
    const float* bout = (const float*)d_in[10];

    char* ws = (char*)d_ws;
    f16*   Wp1 = (f16*)(ws + OFF_WP1);
    f16*   Wp2 = (f16*)(ws + OFF_WP2);
    f16*   Wpo = (f16*)(ws + OFF_WPO);
    float* b1  = (float*)(ws + OFF_B1);
    float* b2  = (float*)(ws + OFF_B2);
    f16*   h1h = (f16*)(ws + OFF_H1H);
    f16*   h2h = (f16*)(ws + OFF_H2H);
    int*   bar = (int*)(ws + OFF_BAR);
    float* zp  = (float*)(ws + OFF_ZP);
    float* out = (float*)d_out;

    // work items: 786432+1048576+16384+4096+4096+65536+4096 = 1929216 -> 7536 blocks
    hipLaunchKernelGGL(pack_kernel, dim3(7536), dim3(256), 0, stream,
                       Wih1, Whh1, Wih2, Whh2, Wout, bih1, bhh1, bih2, bhh2,
                       Wp1, Wp2, Wpo, b1, b2, h1h, h2h, bar);

    void* args[] = { (void*)&x, (void*)&bout, (void*)&Wp1, (void*)&Wp2, (void*)&Wpo,
                     (void*)&b1, (void*)&b2, (void*)&h1h, (void*)&h2h, (void*)&bar,
                     (void*)&zp, (void*)&out };
    hipError_t e = hipLaunchCooperativeKernel((void*)lstm_persist, dim3(256), dim3(256), args, 0, stream);
    if (e != hipSuccess) {
        hipLaunchKernelGGL(lstm_persist, dim3(256), dim3(256), 0, stream,
                           x, bout, Wp1, Wp2, Wpo, b1, b2, h1h, h2h, bar, zp, out);
    }
}